// Round 12
// baseline (132.906 us; speedup 1.0000x reference)
//
#include <hip/hip_runtime.h>
#include <hip/hip_bf16.h>

// ---------------------------------------------------------------------------
// KroneNet fused kernel v12 for MI355X (gfx950)
// out[i][j] = softmax_j( s_a[i] * t_j[i] )
// History: v9/v11 plateau at ~43.5us (VALUBusy 35%, MfmaUtil 14%, LDS ~40%,
// no pipe saturated -> convoy/latency-bound). v10 lesson: interior fences are
// the spill guard. v12: N-SPLIT WAVE PAIRS -- each wave: all 64 samples of
// its pair (mt=4) x half of N (4 n-tiles). W2 fragment reads per MFMA halve;
// per-wave MFMA chain halves; layer-3 partials pair-combined via LDS (+2
// syncthreads); final softmax by full 64-lane wave (coalesced stores).
// ---------------------------------------------------------------------------

#define BTOT 262144
#define NBLK (BTOT / 256)   // 1024 blocks x 512 threads, 256 samples/block

typedef __attribute__((ext_vector_type(2))) float floatx2;
typedef __attribute__((ext_vector_type(4))) float floatx4;
typedef __attribute__((ext_vector_type(8))) short bf16x8;
typedef __attribute__((ext_vector_type(4))) int  intx4;

// LDS layout (bytes), BOTH paths resident
#define OFF_W2  0          // 2 paths * 32768
#define OFF_W1  65536      // 2 paths * 64 pairs * 3 float2 (24B)   = 3072
#define OFF_B2  68608      // 2 paths * 128 * float                 = 1024
#define OFF_W3A 69632      // 128 * float                           = 512
#define OFF_W3B 70144      // 3 * 128 * float                       = 1536
#define OFF_EXA 71680      // 4 pairs * 64 * {half0, half1} float2  = 2048
#define OFF_EXB 73728      // 6 planes (j*2+half) * 4 pairs * 64 f  = 6144
#define LDS_TOTAL 79872    // x2 blocks = 159744 <= 163840 -> 2 blocks/CU

// pack two fp32 -> one dword of two bf16 (gfx950 1-op form, else 3-op)
#if __has_builtin(__builtin_amdgcn_cvt_pk_bf16_f32)
static __device__ __forceinline__ int pack2bf(float lo, float hi) {
    return __builtin_bit_cast(int, __builtin_amdgcn_cvt_pk_bf16_f32(lo, hi));
}
#else
static __device__ __forceinline__ int pack2bf(float lo, float hi) {
    unsigned a = __builtin_bit_cast(unsigned, lo) + 0x8000u;
    unsigned b = __builtin_bit_cast(unsigned, hi) + 0x8000u;
    return (int)__builtin_amdgcn_perm(b, a, 0x07060302u);
}
#endif

// compile-time-indexed 4-way select (NO dynamic register indexing)
#define SEL4(v, i) \
    ((i) == 0 ? (v).x : (i) == 1 ? (v).y : (i) == 2 ? (v).z : (v).w)

static __device__ __forceinline__ floatx4 redcol4(floatx4 v) {
    #pragma unroll
    for (int m = 1; m <= 8; m <<= 1) {
        floatx4 t;
        t.x = __shfl_xor(v.x, m);
        t.y = __shfl_xor(v.y, m);
        t.z = __shfl_xor(v.z, m);
        t.w = __shfl_xor(v.w, m);
        v = v + t;
    }
    return v;
}

static __device__ __forceinline__ floatx4 splat4(float s) {
    return (floatx4){s, s, s, s};
}

// One phase's GEMM over this wave's N-half: acc[t][mt] (t = local n-tile
// 0..3, global n-tile = half*4+t), mt = 0..3 (64 samples). ZERO-C first step.
// acc layout: (t, mt, r) -> sample mt*16+quad*4+r, n = (half*4+t)*16+col.
#define GEMM_PHASE(acc, XV, W1P, W2p)                                          \
    {                                                                          \
        const floatx4 Z4 = (floatx4){0.f, 0.f, 0.f, 0.f};                      \
        _Pragma("unroll")                                                      \
        for (int s = 0; s < 4; ++s) {                                          \
            intx4 af[4];                                                       \
            _Pragma("unroll")                                                  \
            for (int j2 = 0; j2 < 4; ++j2) {                                   \
                int kp = s * 16 + quad * 4 + j2;                               \
                floatx2 w0p = (W1P)[kp * 3];                                   \
                floatx2 w1p = (W1P)[kp * 3 + 1];                               \
                floatx2 b1p = (W1P)[kp * 3 + 2];                               \
                _Pragma("unroll")                                              \
                for (int mt = 0; mt < 4; ++mt) {                               \
                    floatx2 xx = (floatx2){(XV)[mt].x, (XV)[mt].x};            \
                    floatx2 xy = (floatx2){(XV)[mt].y, (XV)[mt].y};            \
                    floatx2 h = __builtin_elementwise_fma(xx, w0p,             \
                                  __builtin_elementwise_fma(xy, w1p, b1p));    \
                    h = __builtin_elementwise_max(h, (floatx2){0.f, 0.f});     \
                    af[mt][j2] = pack2bf(h.x, h.y);                            \
                }                                                              \
            }                                                                  \
            _Pragma("unroll")                                                  \
            for (int t = 0; t < 4; ++t) {                                      \
                bf16x8 bfr = (W2p)[(s * 8 + half * 4 + t) * 64 + lane];        \
                _Pragma("unroll")                                              \
                for (int mt = 0; mt < 4; ++mt) {                               \
                    if (s == 0)                                                \
                        acc[t][mt] = __builtin_amdgcn_mfma_f32_16x16x32_bf16(  \
                            __builtin_bit_cast(bf16x8, af[mt]), bfr, Z4,       \
                            0, 0, 0);                                          \
                    else                                                       \
                        acc[t][mt] = __builtin_amdgcn_mfma_f32_16x16x32_bf16(  \
                            __builtin_bit_cast(bf16x8, af[mt]), bfr,           \
                            acc[t][mt], 0, 0, 0);                              \
                }                                                              \
            }                                                                  \
        }                                                                      \
    }

// ---------------------------------------------------------------------------
// 1024 blocks x 512 threads (8 waves = 4 pairs). Pair p covers samples
// [blk*256 + p*64, +64); wave half h computes n in [h*64, h*64+64).
// pack both paths -> sync -> phase a GEMM+partial -> EXA -> sync ->
// sa combine (all waves, register) -> phase b GEMM+partials -> EXB -> sync
// -> half0 waves: combine + softmax + coalesced store.
// W2 mapping (verified v5-v11). B-frag: lane = quad*16+col holds
// B[k=quad*8+j][n=col].
// ---------------------------------------------------------------------------
__global__ __launch_bounds__(512, 4)
void krone_fused(const float* __restrict__ x,
                 const float* __restrict__ w1a, const float* __restrict__ w1b,
                 const float* __restrict__ b1a, const float* __restrict__ b1b,
                 const float* __restrict__ w2a, const float* __restrict__ w2b,
                 const float* __restrict__ b2a, const float* __restrict__ b2b,
                 const float* __restrict__ w3a, const float* __restrict__ w3b,
                 const float* __restrict__ b3a, const float* __restrict__ b3b,
                 float* __restrict__ out) {
    __shared__ __align__(16) unsigned char smem[LDS_TOTAL];

    const int tid  = threadIdx.x;
    const int lane = tid & 63;
    const int wave = tid >> 6;
    const int quad = lane >> 4;
    const int col  = lane & 15;
    const int pair = wave >> 1;
    const int half = wave & 1;
    const int sbase = blockIdx.x * 256 + pair * 64;   // pair's 64 samples

    // ---- pack both paths into LDS (identical to v9-v11, verified) ----
    {
        #pragma unroll
        for (int i = 0; i < 16; ++i) {
            const int path = i >> 3;
            const float4* w2p = (const float4*)(path ? w2b : w2a);
            int n  = (tid & 15) | ((i & 7) << 4);
            int k4 = tid >> 4;                         // 0..31
            float4 f = w2p[n * 32 + k4];
            int k = k4 * 4;
            int s = k >> 5;
            int j0 = k & 7;                            // 0 or 4
            int l = ((k & 31) >> 3) * 16 + (n & 15);
            int2 pkd;
            pkd.x = pack2bf(f.x, f.y);
            pkd.y = pack2bf(f.z, f.w);
            *(int2*)(smem + OFF_W2 + path * 32768 +
                     (s * 8 + (n >> 4)) * 1024 + l * 16 + j0 * 2) = pkd;
        }
        if (tid < 128) {
            int p = tid >> 6, kp = tid & 63;
            const float* w1 = p ? w1b : w1a;
            const float* b1 = p ? b1b : b1a;
            float4 w4 = ((const float4*)w1)[kp];
            floatx2* dst = (floatx2*)(smem + OFF_W1) + p * 192 + kp * 3;
            dst[0] = (floatx2){w4.x, w4.z};
            dst[1] = (floatx2){w4.y, w4.w};
            dst[2] = (floatx2){b1[2 * kp], b1[2 * kp + 1]};
            ((float*)(smem + OFF_B2))[tid] = b2a[tid];
            ((float*)(smem + OFF_W3A))[tid] = w3a[tid];
        } else if (tid < 256) {
            ((float*)(smem + OFF_B2))[tid] = b2b[tid - 128];
        }
        if (tid >= 128)
            ((float*)(smem + OFF_W3B))[tid - 128] = w3b[tid - 128];
    }

    const bf16x8*  W2A = (const bf16x8*)(smem + OFF_W2);
    const bf16x8*  W2B = (const bf16x8*)(smem + OFF_W2 + 32768);
    const floatx2* W1A = (const floatx2*)(smem + OFF_W1);
    const floatx2* W1B = W1A + 192;
    const float*   B2A = (const float*)(smem + OFF_B2);
    const float*   B2B = B2A + 128;
    const float*   W3A = (const float*)(smem + OFF_W3A);
    const float*   W3B = (const float*)(smem + OFF_W3B);
    float*         EXA = (float*)(smem + OFF_EXA);
    float*         EXB = (float*)(smem + OFF_EXB);
    const float2*  xA  = (const float2*)x;
    const float2*  xB  = xA + BTOT;

    const float b3a_ = b3a[0];                         // uniform -> SGPR
    const float b30 = b3b[0], b31 = b3b[1], b32 = b3b[2];

    // ---- preload x for both phases (issued before the barrier) ----
    float2 xa[4], xb[4];
    #pragma unroll
    for (int mt = 0; mt < 4; ++mt) {
        xa[mt] = xA[sbase + mt * 16 + col];
        xb[mt] = xB[sbase + mt * 16 + col];
    }

    __syncthreads();   // pack complete

    // ================= phase a =================
    __builtin_amdgcn_sched_barrier(0);   // spill guard
    floatx4 acc[4][4];
    GEMM_PHASE(acc, xa, W1A, W2A);
    __builtin_amdgcn_sched_barrier(0);   // GEMM | epilogue

    {
        floatx4 pa[4] = {splat4(0.f), splat4(0.f), splat4(0.f), splat4(0.f)};
        #pragma unroll
        for (int t = 0; t < 4; ++t) {
            int n = (half * 4 + t) * 16 + col;
            floatx4 w4 = splat4(W3A[n]);
            floatx4 b2 = splat4(B2A[n]);
            #pragma unroll
            for (int mt = 0; mt < 4; ++mt) {
                floatx4 h = __builtin_elementwise_max(acc[t][mt] + b2,
                                                      splat4(0.f));
                pa[mt] = __builtin_elementwise_fma(w4, h, pa[mt]);
            }
        }
        #pragma unroll
        for (int mt = 0; mt < 4; ++mt) pa[mt] = redcol4(pa[mt]);
        __builtin_amdgcn_sched_barrier(0);

        if (col < 4) {
            #pragma unroll
            for (int mt = 0; mt < 4; ++mt) {
                int sl = mt * 16 + quad * 4 + col;
                // EXA[(pair*64+sl)*2 + half] -- partner-paired float2 slots
                EXA[(pair * 64 + sl) * 2 + half] = SEL4(pa[mt], col);
            }
        }
    }
    __builtin_amdgcn_sched_barrier(0);
    __syncthreads();   // phase-a partials ready

    // every wave combines its pair's partials into a register (no race)
    float sa;
    {
        floatx2 ex = ((const floatx2*)EXA)[pair * 64 + lane];
        sa = ex.x + ex.y + b3a_;
    }

    // ================= phase b =================
    __builtin_amdgcn_sched_barrier(0);   // spill guard
    GEMM_PHASE(acc, xb, W1B, W2B);
    __builtin_amdgcn_sched_barrier(0);   // GEMM | epilogue

    #pragma unroll
    for (int mt = 0; mt < 4; ++mt) {     // per-mt to cap live partials
        floatx4 p0 = splat4(0.f), p1 = splat4(0.f), p2 = splat4(0.f);
        #pragma unroll
        for (int t = 0; t < 4; ++t) {
            int n = (half * 4 + t) * 16 + col;
            floatx4 b2 = splat4(B2B[n]);
            floatx4 h = __builtin_elementwise_max(acc[t][mt] + b2, splat4(0.f));
            p0 = __builtin_elementwise_fma(splat4(W3B[n]),       h, p0);
            p1 = __builtin_elementwise_fma(splat4(W3B[128 + n]), h, p1);
            p2 = __builtin_elementwise_fma(splat4(W3B[256 + n]), h, p2);
        }
        p0 = redcol4(p0); p1 = redcol4(p1); p2 = redcol4(p2);
        if (col < 4) {
            int sl = mt * 16 + quad * 4 + col;
            // plane (j*2+half): EXB[((j*2+half)*4 + pair)*64 + sl]
            EXB[((0 * 2 + half) * 4 + pair) * 64 + sl] = SEL4(p0, col);
            EXB[((1 * 2 + half) * 4 + pair) * 64 + sl] = SEL4(p1, col);
            EXB[((2 * 2 + half) * 4 + pair) * 64 + sl] = SEL4(p2, col);
        }
    }
    __builtin_amdgcn_sched_barrier(0);
    __syncthreads();   // phase-b partials ready

    if (half == 0) {   // one wave per pair finishes 64 samples, coalesced
        float t0 = EXB[((0 * 2 + 0) * 4 + pair) * 64 + lane]
                 + EXB[((0 * 2 + 1) * 4 + pair) * 64 + lane] + b30;
        float t1 = EXB[((1 * 2 + 0) * 4 + pair) * 64 + lane]
                 + EXB[((1 * 2 + 1) * 4 + pair) * 64 + lane] + b31;
        float t2 = EXB[((2 * 2 + 0) * 4 + pair) * 64 + lane]
                 + EXB[((2 * 2 + 1) * 4 + pair) * 64 + lane] + b32;
        float y0 = sa * t0, y1 = sa * t1, y2 = sa * t2;
        float m = fmaxf(y0, fmaxf(y1, y2));
        float e0 = __expf(y0 - m), e1 = __expf(y1 - m), e2 = __expf(y2 - m);
        float rs = 1.f / (e0 + e1 + e2);
        long o = (long)(sbase + lane) * 3;
        out[o]     = e0 * rs;
        out[o + 1] = e1 * rs;
        out[o + 2] = e2 * rs;
    }
}

extern "C" void kernel_launch(void* const* d_in, const int* in_sizes, int n_in,
                              void* d_out, int out_size, void* d_ws, size_t ws_size,
                              hipStream_t stream) {
    const float* x   = (const float*)d_in[0];
    const float* w1a = (const float*)d_in[1];
    const float* w1b = (const float*)d_in[2];
    const float* b1a = (const float*)d_in[3];
    const float* b1b = (const float*)d_in[4];
    const float* w2a = (const float*)d_in[5];
    const float* w2b = (const float*)d_in[6];
    const float* b2a = (const float*)d_in[7];
    const float* b2b = (const float*)d_in[8];
    const float* w3a = (const float*)d_in[9];
    const float* w3b = (const float*)d_in[10];
    const float* b3a = (const float*)d_in[11];
    const float* b3b = (const float*)d_in[12];
    float* out = (float*)d_out;

    krone_fused<<<NBLK, 512, 0, stream>>>(x, w1a, w1b, b1a, b1b, w2a, w2b,
                                          b2a, b2b, w3a, w3b, b3a, b3b, out);
}

// Round 13
// 129.551 us; speedup vs baseline: 1.0259x; 1.0259x over previous
//
#include <hip/hip_runtime.h>
#include <hip/hip_bf16.h>

// ---------------------------------------------------------------------------
// KroneNet fused kernel v13 for MI355X (gfx950)
// out[i][j] = softmax_j( s_a[i] * t_j[i] )
// History: v9/v11 plateau ~43.5us (2-chunk full-N waves, acc=64, budget
// exactly full, fences = spill guard). v12 N-split mt=4: af[4]+epilogue
// partials blew the 128 budget -> 19MB spill, 65us. LESSON: N-split needs
// acc+af halved too.
// v13: N-split wave pairs with mt=2. acc[4][2]=32 AGPR, af[2]=8 -> ~28 regs
// slack. Per-wave MFMA chain 128 (half of v11). Pair covers 64 samples in 2
// chunks; partials pair-combined via LDS; only chunk-start fences (slack
// hypothesis: spill guard no longer needed at reduced live set).
// ---------------------------------------------------------------------------

#define BTOT 262144
#define NBLK (BTOT / 256)   // 1024 blocks x 512 threads, 256 samples/block

typedef __attribute__((ext_vector_type(2))) float floatx2;
typedef __attribute__((ext_vector_type(4))) float floatx4;
typedef __attribute__((ext_vector_type(8))) short bf16x8;
typedef __attribute__((ext_vector_type(2))) int  intx2;

// LDS layout (bytes), BOTH paths resident
#define OFF_W2  0          // 2 paths * 32768
#define OFF_W1  65536      // 2 paths * 64 pairs * 3 float2 (24B)   = 3072
#define OFF_B2  68608      // 2 paths * 128 * float                 = 1024
#define OFF_W3A 69632      // 128 * float                           = 512
#define OFF_W3B 70144      // 3 * 128 * float                       = 1536
#define OFF_EXA 71680      // 4 pairs * 64 * {half0, half1} float2  = 2048
#define OFF_EXB 73728      // 6 planes (j*2+half) * 4 pairs * 64 f  = 6144
#define LDS_TOTAL 79872    // x2 blocks = 159744 <= 163840 -> 2 blocks/CU

// pack two fp32 -> one dword of two bf16 (gfx950 1-op form, else 3-op)
#if __has_builtin(__builtin_amdgcn_cvt_pk_bf16_f32)
static __device__ __forceinline__ int pack2bf(float lo, float hi) {
    return __builtin_bit_cast(int, __builtin_amdgcn_cvt_pk_bf16_f32(lo, hi));
}
#else
static __device__ __forceinline__ int pack2bf(float lo, float hi) {
    unsigned a = __builtin_bit_cast(unsigned, lo) + 0x8000u;
    unsigned b = __builtin_bit_cast(unsigned, hi) + 0x8000u;
    return (int)__builtin_amdgcn_perm(b, a, 0x07060302u);
}
#endif

// compile-time-indexed 4-way select (NO dynamic register indexing)
#define SEL4(v, i) \
    ((i) == 0 ? (v).x : (i) == 1 ? (v).y : (i) == 2 ? (v).z : (v).w)

static __device__ __forceinline__ floatx4 redcol4(floatx4 v) {
    #pragma unroll
    for (int m = 1; m <= 8; m <<= 1) {
        floatx4 t;
        t.x = __shfl_xor(v.x, m);
        t.y = __shfl_xor(v.y, m);
        t.z = __shfl_xor(v.z, m);
        t.w = __shfl_xor(v.w, m);
        v = v + t;
    }
    return v;
}

static __device__ __forceinline__ floatx4 splat4(float s) {
    return (floatx4){s, s, s, s};
}

// One chunk's GEMM over this wave's N-half: acc[t][mt], t = local n-tile
// (global tile = half*4+t), mt = 0..1 (32 samples). ZERO-C first step.
// acc layout: (t, mt, r) -> sample mt*16+quad*4+r, n = (half*4+t)*16+col.
#define GEMM_CHUNK(acc, XV, W1P, W2p)                                          \
    {                                                                          \
        const floatx4 Z4 = (floatx4){0.f, 0.f, 0.f, 0.f};                      \
        _Pragma("unroll")                                                      \
        for (int s = 0; s < 4; ++s) {                                          \
            intx2 af[2];                                                       \
            _Pragma("unroll")                                                  \
            for (int j2 = 0; j2 < 4; ++j2) {                                   \
                int kp = s * 16 + quad * 4 + j2;                               \
                floatx2 w0p = (W1P)[kp * 3];                                   \
                floatx2 w1p = (W1P)[kp * 3 + 1];                               \
                floatx2 b1p = (W1P)[kp * 3 + 2];                               \
                _Pragma("unroll")                                              \
                for (int mt = 0; mt < 2; ++mt) {                               \
                    floatx2 xx = (floatx2){(XV)[mt].x, (XV)[mt].x};            \
                    floatx2 xy = (floatx2){(XV)[mt].y, (XV)[mt].y};            \
                    floatx2 h = __builtin_elementwise_fma(xx, w0p,             \
                                  __builtin_elementwise_fma(xy, w1p, b1p));    \
                    h = __builtin_elementwise_max(h, (floatx2){0.f, 0.f});     \
                    af[mt][j2 & 1] = pack2bf(h.x, h.y);                        \
                    (void)0;                                                   \
                }                                                              \
                if (j2 == 1 || j2 == 3) {                                      \
                    /* placeholder - real af assembly below */                  \
                }                                                              \
            }                                                                  \
        }                                                                      \
    }

// NOTE: macro above replaced by inline function下面 -- see gemm_chunk().
#undef GEMM_CHUNK

// A-fragment needs 4 dwords (8 bf16) per mt; assemble af[mt] as int4-in-2x
// local arrays then feed MFMA. Simpler: build per-mt intx4 via 4 packs.
typedef __attribute__((ext_vector_type(4))) int intx4;

#define GEMM_CHUNK(acc, XV, W1P, W2p)                                          \
    {                                                                          \
        const floatx4 Z4 = (floatx4){0.f, 0.f, 0.f, 0.f};                      \
        _Pragma("unroll")                                                      \
        for (int s = 0; s < 4; ++s) {                                          \
            intx4 af[2];                                                       \
            _Pragma("unroll")                                                  \
            for (int j2 = 0; j2 < 4; ++j2) {                                   \
                int kp = s * 16 + quad * 4 + j2;                               \
                floatx2 w0p = (W1P)[kp * 3];                                   \
                floatx2 w1p = (W1P)[kp * 3 + 1];                               \
                floatx2 b1p = (W1P)[kp * 3 + 2];                               \
                _Pragma("unroll")                                              \
                for (int mt = 0; mt < 2; ++mt) {                               \
                    floatx2 xx = (floatx2){(XV)[mt].x, (XV)[mt].x};            \
                    floatx2 xy = (floatx2){(XV)[mt].y, (XV)[mt].y};            \
                    floatx2 h = __builtin_elementwise_fma(xx, w0p,             \
                                  __builtin_elementwise_fma(xy, w1p, b1p));    \
                    h = __builtin_elementwise_max(h, (floatx2){0.f, 0.f});     \
                    af[mt][j2] = pack2bf(h.x, h.y);                            \
                }                                                              \
            }                                                                  \
            _Pragma("unroll")                                                  \
            for (int t = 0; t < 4; ++t) {                                      \
                bf16x8 bfr = (W2p)[(s * 8 + half * 4 + t) * 64 + lane];        \
                _Pragma("unroll")                                              \
                for (int mt = 0; mt < 2; ++mt) {                               \
                    if (s == 0)                                                \
                        acc[t][mt] = __builtin_amdgcn_mfma_f32_16x16x32_bf16(  \
                            __builtin_bit_cast(bf16x8, af[mt]), bfr, Z4,       \
                            0, 0, 0);                                          \
                    else                                                       \
                        acc[t][mt] = __builtin_amdgcn_mfma_f32_16x16x32_bf16(  \
                            __builtin_bit_cast(bf16x8, af[mt]), bfr,           \
                            acc[t][mt], 0, 0, 0);                              \
                }                                                              \
            }                                                                  \
        }                                                                      \
    }

// ---------------------------------------------------------------------------
// 1024 blocks x 512 threads (8 waves = 4 pairs). Pair p covers 64 samples
// [blk*256 + p*64, +64) in 2 chunks of 32; wave half h computes n-half h.
// pack -> sync -> phase a (2 chunks, EXA partials) -> sync -> sa combine ->
// phase b (2 chunks, EXB partials) -> sync -> half0 wave: softmax + store.
// W2 mapping (verified v5-v12). B-frag: lane = quad*16+col holds
// B[k=quad*8+j][n=col].
// ---------------------------------------------------------------------------
__global__ __launch_bounds__(512, 4)
void krone_fused(const float* __restrict__ x,
                 const float* __restrict__ w1a, const float* __restrict__ w1b,
                 const float* __restrict__ b1a, const float* __restrict__ b1b,
                 const float* __restrict__ w2a, const float* __restrict__ w2b,
                 const float* __restrict__ b2a, const float* __restrict__ b2b,
                 const float* __restrict__ w3a, const float* __restrict__ w3b,
                 const float* __restrict__ b3a, const float* __restrict__ b3b,
                 float* __restrict__ out) {
    __shared__ __align__(16) unsigned char smem[LDS_TOTAL];

    const int tid  = threadIdx.x;
    const int lane = tid & 63;
    const int wave = tid >> 6;
    const int quad = lane >> 4;
    const int col  = lane & 15;
    const int pair = wave >> 1;
    const int half = wave & 1;
    const int sbase = blockIdx.x * 256 + pair * 64;   // pair's 64 samples

    // ---- pack both paths into LDS (identical to v9-v12, verified) ----
    {
        #pragma unroll
        for (int i = 0; i < 16; ++i) {
            const int path = i >> 3;
            const float4* w2p = (const float4*)(path ? w2b : w2a);
            int n  = (tid & 15) | ((i & 7) << 4);
            int k4 = tid >> 4;                         // 0..31
            float4 f = w2p[n * 32 + k4];
            int k = k4 * 4;
            int s = k >> 5;
            int j0 = k & 7;                            // 0 or 4
            int l = ((k & 31) >> 3) * 16 + (n & 15);
            int2 pkd;
            pkd.x = pack2bf(f.x, f.y);
            pkd.y = pack2bf(f.z, f.w);
            *(int2*)(smem + OFF_W2 + path * 32768 +
                     (s * 8 + (n >> 4)) * 1024 + l * 16 + j0 * 2) = pkd;
        }
        if (tid < 128) {
            int p = tid >> 6, kp = tid & 63;
            const float* w1 = p ? w1b : w1a;
            const float* b1 = p ? b1b : b1a;
            float4 w4 = ((const float4*)w1)[kp];
            floatx2* dst = (floatx2*)(smem + OFF_W1) + p * 192 + kp * 3;
            dst[0] = (floatx2){w4.x, w4.z};
            dst[1] = (floatx2){w4.y, w4.w};
            dst[2] = (floatx2){b1[2 * kp], b1[2 * kp + 1]};
            ((float*)(smem + OFF_B2))[tid] = b2a[tid];
            ((float*)(smem + OFF_W3A))[tid] = w3a[tid];
        } else if (tid < 256) {
            ((float*)(smem + OFF_B2))[tid] = b2b[tid - 128];
        }
        if (tid >= 128)
            ((float*)(smem + OFF_W3B))[tid - 128] = w3b[tid - 128];
    }

    const bf16x8*  W2A = (const bf16x8*)(smem + OFF_W2);
    const bf16x8*  W2B = (const bf16x8*)(smem + OFF_W2 + 32768);
    const floatx2* W1A = (const floatx2*)(smem + OFF_W1);
    const floatx2* W1B = W1A + 192;
    const float*   B2A = (const float*)(smem + OFF_B2);
    const float*   B2B = B2A + 128;
    const float*   W3A = (const float*)(smem + OFF_W3A);
    const float*   W3B = (const float*)(smem + OFF_W3B);
    float*         EXA = (float*)(smem + OFF_EXA);
    float*         EXB = (float*)(smem + OFF_EXB);
    const float2*  xA  = (const float2*)x;
    const float2*  xB  = xA + BTOT;

    const float b3a_ = b3a[0];                         // uniform -> SGPR
    const float b30 = b3b[0], b31 = b3b[1], b32 = b3b[2];

    // ---- preload x for both phases (issued before the barrier) ----
    float2 xa[4], xb[4];   // [c*2 + mt]
    #pragma unroll
    for (int c = 0; c < 2; ++c)
        #pragma unroll
        for (int mt = 0; mt < 2; ++mt) {
            int idx = sbase + c * 32 + mt * 16 + col;
            xa[c * 2 + mt] = xA[idx];
            xb[c * 2 + mt] = xB[idx];
        }

    __syncthreads();   // pack complete

    // ================= phase a: 2 chunks of 32 samples =================
    #pragma unroll
    for (int c = 0; c < 2; ++c) {
        __builtin_amdgcn_sched_barrier(0);   // chunk start
        floatx4 acc[4][2];
        GEMM_CHUNK(acc, xa + 2 * c, W1A, W2A);

        floatx4 pa[2] = {splat4(0.f), splat4(0.f)};
        #pragma unroll
        for (int t = 0; t < 4; ++t) {
            int n = (half * 4 + t) * 16 + col;
            floatx4 w4 = splat4(W3A[n]);
            floatx4 b2 = splat4(B2A[n]);
            #pragma unroll
            for (int mt = 0; mt < 2; ++mt) {
                floatx4 h = __builtin_elementwise_max(acc[t][mt] + b2,
                                                      splat4(0.f));
                pa[mt] = __builtin_elementwise_fma(w4, h, pa[mt]);
            }
        }
        #pragma unroll
        for (int mt = 0; mt < 2; ++mt) pa[mt] = redcol4(pa[mt]);

        if (col < 4) {
            #pragma unroll
            for (int mt = 0; mt < 2; ++mt) {
                int sl = c * 32 + mt * 16 + quad * 4 + col;
                EXA[(pair * 64 + sl) * 2 + half] = SEL4(pa[mt], col);
            }
        }
    }
    __syncthreads();   // phase-a partials ready

    // every wave combines its pair's partials into a register (no race)
    float sa;
    {
        floatx2 ex = ((const floatx2*)EXA)[pair * 64 + lane];
        sa = ex.x + ex.y + b3a_;
    }

    // ================= phase b: 2 chunks of 32 samples =================
    #pragma unroll
    for (int c = 0; c < 2; ++c) {
        __builtin_amdgcn_sched_barrier(0);   // chunk start
        floatx4 acc[4][2];
        GEMM_CHUNK(acc, xb + 2 * c, W1B, W2B);

        #pragma unroll
        for (int mt = 0; mt < 2; ++mt) {
            floatx4 p0 = splat4(0.f), p1 = splat4(0.f), p2 = splat4(0.f);
            #pragma unroll
            for (int t = 0; t < 4; ++t) {
                int n = (half * 4 + t) * 16 + col;
                floatx4 b2 = splat4(B2B[n]);
                floatx4 h = __builtin_elementwise_max(acc[t][mt] + b2,
                                                      splat4(0.f));
                p0 = __builtin_elementwise_fma(splat4(W3B[n]),       h, p0);
                p1 = __builtin_elementwise_fma(splat4(W3B[128 + n]), h, p1);
                p2 = __builtin_elementwise_fma(splat4(W3B[256 + n]), h, p2);
            }
            p0 = redcol4(p0); p1 = redcol4(p1); p2 = redcol4(p2);
            if (col < 4) {
                int sl = c * 32 + mt * 16 + quad * 4 + col;
                EXB[((0 * 2 + half) * 4 + pair) * 64 + sl] = SEL4(p0, col);
                EXB[((1 * 2 + half) * 4 + pair) * 64 + sl] = SEL4(p1, col);
                EXB[((2 * 2 + half) * 4 + pair) * 64 + sl] = SEL4(p2, col);
            }
        }
    }
    __syncthreads();   // phase-b partials ready

    if (half == 0) {   // one wave per pair finishes 64 samples, coalesced
        float t0 = EXB[((0 * 2 + 0) * 4 + pair) * 64 + lane]
                 + EXB[((0 * 2 + 1) * 4 + pair) * 64 + lane] + b30;
        float t1 = EXB[((1 * 2 + 0) * 4 + pair) * 64 + lane]
                 + EXB[((1 * 2 + 1) * 4 + pair) * 64 + lane] + b31;
        float t2 = EXB[((2 * 2 + 0) * 4 + pair) * 64 + lane]
                 + EXB[((2 * 2 + 1) * 4 + pair) * 64 + lane] + b32;
        float y0 = sa * t0, y1 = sa * t1, y2 = sa * t2;
        float m = fmaxf(y0, fmaxf(y1, y2));
        float e0 = __expf(y0 - m), e1 = __expf(y1 - m), e2 = __expf(y2 - m);
        float rs = 1.f / (e0 + e1 + e2);
        long o = (long)(sbase + lane) * 3;
        out[o]     = e0 * rs;
        out[o + 1] = e1 * rs;
        out[o + 2] = e2 * rs;
    }
}

extern "C" void kernel_launch(void* const* d_in, const int* in_sizes, int n_in,
                              void* d_out, int out_size, void* d_ws, size_t ws_size,
                              hipStream_t stream) {
    const float* x   = (const float*)d_in[0];
    const float* w1a = (const float*)d_in[1];
    const float* w1b = (const float*)d_in[2];
    const float* b1a = (const float*)d_in[3];
    const float* b1b = (const float*)d_in[4];
    const float* w2a = (const float*)d_in[5];
    const float* w2b = (const float*)d_in[6];
    const float* b2a = (const float*)d_in[7];
    const float* b2b = (const float*)d_in[8];
    const float* w3a = (const float*)d_in[9];
    const float* w3b = (const float*)d_in[10];
    const float* b3a = (const float*)d_in[11];
    const float* b3b = (const float*)d_in[12];
    float* out = (float*)d_out;

    krone_fused<<<NBLK, 512, 0, stream>>>(x, w1a, w1b, b1a, b1b, w2a, w2b,
                                          b2a, b2b, w3a, w3b, b3a, b3b, out);
}